// Round 1
// baseline (297.446 us; speedup 1.0000x reference)
//
#include <hip/hip_runtime.h>
#include <cmath>

#define HH 1024
#define WW 1024
#define KS 51
#define RAD 25
#define PLANE (HH * WW)

struct GaussW { float w[KS]; };

// ---------------------------------------------------------------------------
// Horizontal 51-tap blur. One block = 2 rows, 128 threads/row, 8 outputs/thread.
// Padded LDS row (zero halo) -> no bounds checks. Register sliding window:
// 15 ds_read_b128 per thread feeds 408 FMAs (weights live in SGPRs via kernarg).
// ---------------------------------------------------------------------------
__global__ __launch_bounds__(256) void hblur_kernel(const float* __restrict__ x,
                                                    float* __restrict__ tmp,
                                                    GaussW gw)
{
    __shared__ float lrow[2][1080];   // [25 zero | 1024 data | 31 zero] per row
    const int t   = threadIdx.x;
    const int r   = t >> 7;           // which of the 2 rows in this block
    const int tid = t & 127;
    const long long row = (long long)blockIdx.x * 2 + r;
    const float* src = x + row * WW;

    const int j0 = tid * 8;
    float4 a = *(const float4*)(src + j0);
    float4 b = *(const float4*)(src + j0 + 4);
    *(float4*)(&lrow[r][25 + j0])     = a;
    *(float4*)(&lrow[r][25 + j0 + 4]) = b;
    if (tid < 25) lrow[r][tid] = 0.f;          // left zero pad
    if (tid < 31) lrow[r][1049 + tid] = 0.f;   // right zero pad (covers overread)
    __syncthreads();

    // register window: outputs j0..j0+7 need lds[j0 .. j0+57]; load 60 (16B aligned)
    float win[60];
    #pragma unroll
    for (int i = 0; i < 15; i++)
        *(float4*)(&win[i * 4]) = *(const float4*)(&lrow[r][j0 + i * 4]);

    float acc[8];
    #pragma unroll
    for (int d = 0; d < 8; d++) acc[d] = 0.f;
    #pragma unroll
    for (int k = 0; k < KS; k++) {
        const float wk = gw.w[k];     // SGPR (kernarg), free operand of v_fmac
        #pragma unroll
        for (int d = 0; d < 8; d++) acc[d] = fmaf(wk, win[d + k], acc[d]);
    }

    float* dst = tmp + row * WW;
    *(float4*)(dst + j0)     = make_float4(acc[0], acc[1], acc[2], acc[3]);
    *(float4*)(dst + j0 + 4) = make_float4(acc[4], acc[5], acc[6], acc[7]);
}

// ---------------------------------------------------------------------------
// Vertical 51-tap blur fused with screen-blend + clamp.
// Block = 64 cols x 64 rows tile; thread = 1 col x 16 rows.
// 66 coalesced loads -> 816 register FMAs (input-stationary). Row-bound checks
// are wave-uniform (one wave = one row-group). Consecutive blocks walk tile_y
// so vertical halo refetches hit L2.
// ---------------------------------------------------------------------------
__global__ __launch_bounds__(256) void vblend_kernel(const float* __restrict__ tmp,
                                                     const float* __restrict__ x,
                                                     float* __restrict__ out,
                                                     GaussW gw,
                                                     const float* __restrict__ amountp)
{
    const int t      = threadIdx.x;
    const int bid    = blockIdx.x;
    const int plane  = bid >> 8;          // 256 tiles per plane
    const int rem    = bid & 255;
    const int tile_x = rem >> 4;
    const int tile_y = rem & 15;          // inner -> vertical neighbors adjacent
    const int col    = tile_x * 64 + (t & 63);
    const int r0     = tile_y * 64 + (t >> 6) * 16;

    const float* tp = tmp + (size_t)plane * PLANE + col;

    float acc[16];
    #pragma unroll
    for (int j = 0; j < 16; j++) acc[j] = 0.f;

    #pragma unroll
    for (int i = 0; i < 66; i++) {
        const int ri = r0 - RAD + i;
        float v = 0.f;
        if (ri >= 0 && ri < HH) v = tp[(size_t)ri * WW];   // wave-uniform branch
        #pragma unroll
        for (int j = 0; j < 16; j++) {
            const int k = j - i + 50;        // compile-time tap index
            if (k >= 0 && k < KS)
                acc[j] = fmaf(gw.w[k], v, acc[j]);
        }
    }

    const float p = amountp[0];
    const float s = 1.2f * (0.4f / (1.f + expf(-p)));   // 1.2 * amount

    const float* xp = x   + (size_t)plane * PLANE + col;
    float*       op = out + (size_t)plane * PLANE + col;
    #pragma unroll
    for (int j = 0; j < 16; j++) {
        const float xv  = xp[(size_t)(r0 + j) * WW];
        float res = 1.f - (1.f - xv) * (1.f - s * acc[j]);
        res = fminf(fmaxf(res, 0.f), 1.f);
        op[(size_t)(r0 + j) * WW] = res;
    }
}

// ---------------------------------------------------------------------------
extern "C" void kernel_launch(void* const* d_in, const int* in_sizes, int n_in,
                              void* d_out, int out_size, void* d_ws, size_t ws_size,
                              hipStream_t stream)
{
    const float* x       = (const float*)d_in[0];
    const float* amountp = (const float*)d_in[1];
    float* out = (float*)d_out;
    float* tmp = (float*)d_ws;

    // Gaussian weights (sigma=15, size 51), normalized — same every call.
    GaussW gw;
    {
        double e[KS], sum = 0.0;
        for (int i = 0; i < KS; i++) {
            const double d = (double)(i - RAD);
            e[i] = exp(-d * d / (2.0 * 15.0 * 15.0));
            sum += e[i];
        }
        for (int i = 0; i < KS; i++) gw.w[i] = (float)(e[i] / sum);
    }

    const int total_planes = in_sizes[0] / PLANE;      // 8*3 = 24
    const size_t plane_bytes = (size_t)PLANE * sizeof(float);
    int P = (int)(ws_size / plane_bytes);              // planes per chunk
    if (P < 1) P = 1;
    if (P > total_planes) P = total_planes;

    for (int p0 = 0; p0 < total_planes; p0 += P) {
        const int pc = (total_planes - p0 < P) ? (total_planes - p0) : P;
        hblur_kernel<<<pc * 512, 256, 0, stream>>>(x + (size_t)p0 * PLANE, tmp, gw);
        vblend_kernel<<<pc * 256, 256, 0, stream>>>(tmp,
                                                    x + (size_t)p0 * PLANE,
                                                    out + (size_t)p0 * PLANE,
                                                    gw, amountp);
    }
}